// Round 1
// baseline (606.386 us; speedup 1.0000x reference)
//
#include <hip/hip_runtime.h>

// ContextAddition: B=2048, SEQ=77, DIM=768, EOT=49407, CA_LEN=DA_LEN=8
// Composition of the two _insert_postfix calls gives, per row (e=eot, d=dyn):
//   p < e          : emb[tok[p]]
//   e <= p < e+8   : da[p-e]
//   d:  e+8<=p<e+16: ca[p-e-8];   p>=e+16: emb[tok[p-16]]
//   !d: p>=e+8     : emb[tok[p-8]]

#define NB    2048
#define SEQ_  77
#define DIM_  768
#define EOT_  49407
#define LV_   8

__global__ __launch_bounds__(256) void ctx_add_kernel(
    const int*   __restrict__ tokens,   // (B, SEQ)
    const int*   __restrict__ dyn,      // (B,) bool-as-int
    const float* __restrict__ emb,      // (VOCAB, DIM)
    const float* __restrict__ ca,       // (8, DIM)
    const float* __restrict__ da,       // (8, DIM)
    float*       __restrict__ out)      // (B, SEQ, DIM)
{
    const int b   = blockIdx.x;
    const int tid = threadIdx.x;

    __shared__ const float* srcp[SEQ_];
    __shared__ int s_eot;

    const int* trow = tokens + b * SEQ_;

    if (tid == 0) s_eot = SEQ_;   // "not found" -> everything is plain gather
    __syncthreads();
    if (tid < SEQ_ && trow[tid] == EOT_) atomicMin(&s_eot, tid);
    __syncthreads();

    const int  e = s_eot;
    const bool d = dyn[b] != 0;

    if (tid < SEQ_) {
        const int p = tid;
        const float* sp;
        if (p < e) {
            sp = emb + (size_t)trow[p] * DIM_;
        } else if (p < e + LV_) {
            sp = da + (p - e) * DIM_;
        } else if (d) {
            if (p < e + 2 * LV_) sp = ca + (p - e - LV_) * DIM_;
            else                 sp = emb + (size_t)trow[p - 2 * LV_] * DIM_;
        } else {
            sp = emb + (size_t)trow[p - LV_] * DIM_;
        }
        srcp[p] = sp;
    }
    __syncthreads();

    // Copy 77 rows x 768 floats as float4 (all bases 3072B-aligned).
    float4* __restrict__ orow = (float4*)(out + (size_t)b * SEQ_ * DIM_);
    const int wave = tid >> 6;
    const int lane = tid & 63;
    for (int p = wave; p < SEQ_; p += 4) {
        const float4* sp4 = (const float4*)srcp[p];
        float4*       op4 = orow + p * (DIM_ / 4);
        #pragma unroll
        for (int c = 0; c < DIM_ / 4; c += 64) {
            op4[c + lane] = sp4[c + lane];
        }
    }
}

extern "C" void kernel_launch(void* const* d_in, const int* in_sizes, int n_in,
                              void* d_out, int out_size, void* d_ws, size_t ws_size,
                              hipStream_t stream) {
    const int*   tokens = (const int*)  d_in[0];
    const int*   dyn    = (const int*)  d_in[1];
    const float* emb    = (const float*)d_in[2];
    const float* ca     = (const float*)d_in[3];
    const float* da     = (const float*)d_in[4];
    float*       out    = (float*)d_out;

    ctx_add_kernel<<<NB, 256, 0, stream>>>(tokens, dyn, emb, ca, da, out);
}